// Round 3
// baseline (37.090 us; speedup 1.0000x reference)
//
#include <hip/hip_runtime.h>
#include <math.h>

#define S_DIM 2048
#define B_DIM 64
#define F_DIM 512
// output: (B, 3*F) = [last, mean, max]

// Kernel 1: per (batch, chunk) partial sum + max over INTERLEAVED rows
// s = chunk + n_chunks * j. Interleaving balances work across the chunks of
// one batch; putting BATCH on blockIdx.x (fast-moving) decorrelates CU
// assignment from batch length, so every CU's resident blocks sample many
// different batches -> balanced CU work.
__global__ __launch_bounds__(128) void scp_partial(const float* __restrict__ x,
                                                   const int* __restrict__ lengths,
                                                   float* __restrict__ ws,
                                                   int n_chunks) {
    const int b = blockIdx.x;           // fast dim = batch (decorrelate len)
    const int c = blockIdx.y;           // chunk
    const int f = threadIdx.x * 4;      // 128 threads x float4 = 512 floats
    const int len = lengths[b];

    float4 sum = make_float4(0.f, 0.f, 0.f, 0.f);
    float4 mx = make_float4(-INFINITY, -INFINITY, -INFINITY, -INFINITY);

    const size_t row_stride = (size_t)B_DIM * F_DIM;
    const float* p = x + (size_t)c * row_stride + (size_t)b * F_DIM + f;
    const size_t step = (size_t)n_chunks * row_stride;

    const int cnt = (len > c) ? (len - c + n_chunks - 1) / n_chunks : 0;

    #pragma unroll 4
    for (int j = 0; j < cnt; ++j) {
        float4 v = *reinterpret_cast<const float4*>(p);
        sum.x += v.x; sum.y += v.y; sum.z += v.z; sum.w += v.w;
        mx.x = fmaxf(mx.x, v.x);
        mx.y = fmaxf(mx.y, v.y);
        mx.z = fmaxf(mx.z, v.z);
        mx.w = fmaxf(mx.w, v.w);
        p += step;
    }

    float* dst = ws + (size_t)(b * n_chunks + c) * (2 * F_DIM);
    *reinterpret_cast<float4*>(dst + f) = sum;
    *reinterpret_cast<float4*>(dst + F_DIM + f) = mx;
}

// Kernel 2: combine chunk partials (chunk-parallel, LDS reduce), fetch last
// row, write [last, mean, max]. Grid (B, 4): block (b,y) owns features
// [y*128, (y+1)*128). 128 threads = 32 float4-groups x 4-way chunk split.
__global__ __launch_bounds__(128) void scp_finalize(const float* __restrict__ x,
                                                    const int* __restrict__ lengths,
                                                    const float* __restrict__ ws,
                                                    float* __restrict__ out,
                                                    int n_chunks) {
    const int b = blockIdx.x;
    const int y = blockIdx.y;           // feature quarter
    const int tid = threadIdx.x;
    const int f4l = tid & 31;           // 32 float4 groups = 128 floats
    const int cpar = tid >> 5;          // 0..3 chunk-split lane
    const int f = y * 128 + f4l * 4;
    const int len = lengths[b];

    // issue last-row load early; latency hides under partial reads
    const float4 last = *reinterpret_cast<const float4*>(
        x + ((size_t)(len - 1) * B_DIM + b) * F_DIM + f);

    float4 sum = make_float4(0.f, 0.f, 0.f, 0.f);
    float4 mx = make_float4(-INFINITY, -INFINITY, -INFINITY, -INFINITY);

    for (int c = cpar; c < n_chunks; c += 4) {
        const float* src = ws + (size_t)(b * n_chunks + c) * (2 * F_DIM);
        float4 s4 = *reinterpret_cast<const float4*>(src + f);
        float4 m4 = *reinterpret_cast<const float4*>(src + F_DIM + f);
        sum.x += s4.x; sum.y += s4.y; sum.z += s4.z; sum.w += s4.w;
        mx.x = fmaxf(mx.x, m4.x);
        mx.y = fmaxf(mx.y, m4.y);
        mx.z = fmaxf(mx.z, m4.z);
        mx.w = fmaxf(mx.w, m4.w);
    }

    __shared__ float4 ssum[4][32];
    __shared__ float4 smax[4][32];
    ssum[cpar][f4l] = sum;
    smax[cpar][f4l] = mx;
    __syncthreads();

    if (cpar == 0) {
        for (int k = 1; k < 4; ++k) {
            float4 s4 = ssum[k][f4l];
            float4 m4 = smax[k][f4l];
            sum.x += s4.x; sum.y += s4.y; sum.z += s4.z; sum.w += s4.w;
            mx.x = fmaxf(mx.x, m4.x);
            mx.y = fmaxf(mx.y, m4.y);
            mx.z = fmaxf(mx.z, m4.z);
            mx.w = fmaxf(mx.w, m4.w);
        }

        const float inv = 1.0f / (float)len;
        float4 mean = make_float4(sum.x * inv, sum.y * inv, sum.z * inv, sum.w * inv);

        float* ob = out + (size_t)b * (3 * F_DIM);
        *reinterpret_cast<float4*>(ob + f) = last;
        *reinterpret_cast<float4*>(ob + F_DIM + f) = mean;
        *reinterpret_cast<float4*>(ob + 2 * F_DIM + f) = mx;
    }
}

extern "C" void kernel_launch(void* const* d_in, const int* in_sizes, int n_in,
                              void* d_out, int out_size, void* d_ws, size_t ws_size,
                              hipStream_t stream) {
    const float* x = (const float*)d_in[0];
    const int* lengths = (const int*)d_in[1];
    float* out = (float*)d_out;
    float* ws = (float*)d_ws;

    int n_chunks = 64;
    size_t need = (size_t)B_DIM * n_chunks * 2 * F_DIM * sizeof(float);
    while (n_chunks > 4 && need > ws_size) { n_chunks >>= 1; need >>= 1; }

    scp_partial<<<dim3(B_DIM, n_chunks), 128, 0, stream>>>(x, lengths, ws, n_chunks);
    scp_finalize<<<dim3(B_DIM, 4), 128, 0, stream>>>(x, lengths, ws, out, n_chunks);
}

// Round 4
// 36.868 us; speedup vs baseline: 1.0060x; 1.0060x over previous
//
#include <hip/hip_runtime.h>
#include <hip/hip_bf16.h>
#include <math.h>

#define S_DIM 2048
#define B_DIM 64
#define F_DIM 512
// output: (B, 3*F) = [last, mean, max]

typedef float f32x4 __attribute__((ext_vector_type(4)));

__device__ __forceinline__ ushort bf16_bits(float v) {
    __hip_bfloat16 h = __float2bfloat16(v);   // round-to-nearest
    return *reinterpret_cast<ushort*>(&h);
}
__device__ __forceinline__ float bf16_val(ushort u) {
    __hip_bfloat16 h = *reinterpret_cast<__hip_bfloat16*>(&u);
    return __bfloat162float(h);
}

// Kernel 1: per (chunk, batch) partial sum + max over INTERLEAVED rows
// s = chunk + n_chunks * j. Grid is (x=chunk, y=batch): CU k's resident
// blocks then have chunk = k%64 fixed and 16 DISTINCT batches (round-robin
// block->CU over linear id), decorrelating CU work from batch length.
// Partials stored as bf16 (1KB sum + 1KB max per (b,c)) to halve ws traffic.
__global__ __launch_bounds__(128) void scp_partial(const float* __restrict__ x,
                                                   const int* __restrict__ lengths,
                                                   ushort* __restrict__ ws,
                                                   int n_chunks) {
    const int c = blockIdx.x;           // fast dim = chunk
    const int b = blockIdx.y;           // slow dim = batch
    const int f = threadIdx.x * 4;      // 128 threads x float4 = 512 floats
    const int len = lengths[b];

    float4 sum = make_float4(0.f, 0.f, 0.f, 0.f);
    float4 mx = make_float4(-INFINITY, -INFINITY, -INFINITY, -INFINITY);

    const size_t row_stride = (size_t)B_DIM * F_DIM;
    const float* p = x + (size_t)c * row_stride + (size_t)b * F_DIM + f;
    const size_t step = (size_t)n_chunks * row_stride;

    const int cnt = (len > c) ? (len - c + n_chunks - 1) / n_chunks : 0;

    #pragma unroll 4
    for (int j = 0; j < cnt; ++j) {
        // x is streamed exactly once -> non-temporal, keep L2/L3 for partials
        f32x4 v = __builtin_nontemporal_load(reinterpret_cast<const f32x4*>(p));
        sum.x += v.x; sum.y += v.y; sum.z += v.z; sum.w += v.w;
        mx.x = fmaxf(mx.x, v.x);
        mx.y = fmaxf(mx.y, v.y);
        mx.z = fmaxf(mx.z, v.z);
        mx.w = fmaxf(mx.w, v.w);
        p += step;
    }

    // layout per (b,c): [0,512) bf16 sums, [512,1024) bf16 maxes
    ushort* dst = ws + (size_t)(b * n_chunks + c) * (2 * F_DIM);
    ushort4 us, um;
    us.x = bf16_bits(sum.x); us.y = bf16_bits(sum.y);
    us.z = bf16_bits(sum.z); us.w = bf16_bits(sum.w);
    um.x = bf16_bits(mx.x);  um.y = bf16_bits(mx.y);
    um.z = bf16_bits(mx.z);  um.w = bf16_bits(mx.w);
    *reinterpret_cast<ushort4*>(dst + f) = us;
    *reinterpret_cast<ushort4*>(dst + F_DIM + f) = um;
}

// Kernel 2: combine chunk partials (chunk-parallel, LDS reduce), fetch last
// row, write [last, mean, max]. Grid (B, 4): block (b,y) owns features
// [y*128, (y+1)*128). 128 threads = 32 float4-groups x 4-way chunk split.
__global__ __launch_bounds__(128) void scp_finalize(const float* __restrict__ x,
                                                    const int* __restrict__ lengths,
                                                    const ushort* __restrict__ ws,
                                                    float* __restrict__ out,
                                                    int n_chunks) {
    const int b = blockIdx.x;
    const int y = blockIdx.y;           // feature quarter
    const int tid = threadIdx.x;
    const int f4l = tid & 31;           // 32 float4 groups = 128 floats
    const int cpar = tid >> 5;          // 0..3 chunk-split lane
    const int f = y * 128 + f4l * 4;
    const int len = lengths[b];

    // issue last-row load early; latency hides under partial reads
    const float4 last = *reinterpret_cast<const float4*>(
        x + ((size_t)(len - 1) * B_DIM + b) * F_DIM + f);

    float4 sum = make_float4(0.f, 0.f, 0.f, 0.f);
    float4 mx = make_float4(-INFINITY, -INFINITY, -INFINITY, -INFINITY);

    for (int c = cpar; c < n_chunks; c += 4) {
        const ushort* src = ws + (size_t)(b * n_chunks + c) * (2 * F_DIM);
        ushort4 s4 = *reinterpret_cast<const ushort4*>(src + f);
        ushort4 m4 = *reinterpret_cast<const ushort4*>(src + F_DIM + f);
        sum.x += bf16_val(s4.x); sum.y += bf16_val(s4.y);
        sum.z += bf16_val(s4.z); sum.w += bf16_val(s4.w);
        mx.x = fmaxf(mx.x, bf16_val(m4.x));
        mx.y = fmaxf(mx.y, bf16_val(m4.y));
        mx.z = fmaxf(mx.z, bf16_val(m4.z));
        mx.w = fmaxf(mx.w, bf16_val(m4.w));
    }

    __shared__ float4 ssum[4][32];
    __shared__ float4 smax[4][32];
    ssum[cpar][f4l] = sum;
    smax[cpar][f4l] = mx;
    __syncthreads();

    if (cpar == 0) {
        for (int k = 1; k < 4; ++k) {
            float4 s4 = ssum[k][f4l];
            float4 m4 = smax[k][f4l];
            sum.x += s4.x; sum.y += s4.y; sum.z += s4.z; sum.w += s4.w;
            mx.x = fmaxf(mx.x, m4.x);
            mx.y = fmaxf(mx.y, m4.y);
            mx.z = fmaxf(mx.z, m4.z);
            mx.w = fmaxf(mx.w, m4.w);
        }

        const float inv = 1.0f / (float)len;
        float4 mean = make_float4(sum.x * inv, sum.y * inv, sum.z * inv, sum.w * inv);

        float* ob = out + (size_t)b * (3 * F_DIM);
        *reinterpret_cast<float4*>(ob + f) = last;
        *reinterpret_cast<float4*>(ob + F_DIM + f) = mean;
        *reinterpret_cast<float4*>(ob + 2 * F_DIM + f) = mx;
    }
}

extern "C" void kernel_launch(void* const* d_in, const int* in_sizes, int n_in,
                              void* d_out, int out_size, void* d_ws, size_t ws_size,
                              hipStream_t stream) {
    const float* x = (const float*)d_in[0];
    const int* lengths = (const int*)d_in[1];
    float* out = (float*)d_out;
    ushort* ws = (ushort*)d_ws;

    int n_chunks = 64;
    size_t need = (size_t)B_DIM * n_chunks * 2 * F_DIM * sizeof(ushort);
    while (n_chunks > 4 && need > ws_size) { n_chunks >>= 1; need >>= 1; }

    scp_partial<<<dim3(n_chunks, B_DIM), 128, 0, stream>>>(x, lengths, ws, n_chunks);
    scp_finalize<<<dim3(B_DIM, 4), 128, 0, stream>>>(x, lengths, ws, out, n_chunks);
}

// Round 5
// 33.040 us; speedup vs baseline: 1.1226x; 1.1159x over previous
//
#include <hip/hip_runtime.h>
#include <hip/hip_bf16.h>
#include <math.h>

#define S_DIM 2048
#define B_DIM 64
#define F_DIM 512
#define NCHUNK 128          // chunks per batch; 8192 blocks = 2x residency -> HW refill balances
// output: (B, 3*F) = [last, mean, max]

__device__ __forceinline__ ushort bf16_bits(float v) {
    __hip_bfloat16 h = __float2bfloat16(v);   // round-to-nearest
    return *reinterpret_cast<ushort*>(&h);
}
__device__ __forceinline__ float bf16_val(ushort u) {
    __hip_bfloat16 h = *reinterpret_cast<__hip_bfloat16*>(&u);
    return __bfloat162float(h);
}

// Kernel 1: per (chunk, batch) partial sum + max over INTERLEAVED rows
// s = c + NCHUNK * j. 8192 blocks vs 4096 resident slots: the second half is
// dispatched into CUs as they free -> dynamic load balancing without atomics.
// Partials stored bf16: 2KB per tile, 16MB total.
__global__ __launch_bounds__(128) void scp_partial(const float* __restrict__ x,
                                                   const int* __restrict__ lengths,
                                                   ushort* __restrict__ ws) {
    const int c = blockIdx.x;           // chunk (fast dim)
    const int b = blockIdx.y;           // batch
    const int f = threadIdx.x * 4;      // 128 threads x float4 = 512 floats
    const int len = lengths[b];

    float4 sum = make_float4(0.f, 0.f, 0.f, 0.f);
    float4 mx = make_float4(-INFINITY, -INFINITY, -INFINITY, -INFINITY);

    const size_t row_stride = (size_t)B_DIM * F_DIM;
    const float* p = x + (size_t)c * row_stride + (size_t)b * F_DIM + f;
    const size_t step = (size_t)NCHUNK * row_stride;

    const int cnt = (len > c) ? (len - c + NCHUNK - 1) >> 7 : 0;

    #pragma unroll 4
    for (int j = 0; j < cnt; ++j) {
        float4 v = *reinterpret_cast<const float4*>(p);
        sum.x += v.x; sum.y += v.y; sum.z += v.z; sum.w += v.w;
        mx.x = fmaxf(mx.x, v.x);
        mx.y = fmaxf(mx.y, v.y);
        mx.z = fmaxf(mx.z, v.z);
        mx.w = fmaxf(mx.w, v.w);
        p += step;
    }

    // layout per (b,c): [0,512) bf16 sums, [512,1024) bf16 maxes (ushort units)
    ushort* dst = ws + ((size_t)b * NCHUNK + c) * (2 * F_DIM);
    ushort4 us, um;
    us.x = bf16_bits(sum.x); us.y = bf16_bits(sum.y);
    us.z = bf16_bits(sum.z); us.w = bf16_bits(sum.w);
    um.x = bf16_bits(mx.x);  um.y = bf16_bits(mx.y);
    um.z = bf16_bits(mx.z);  um.w = bf16_bits(mx.w);
    *reinterpret_cast<ushort4*>(dst + f) = us;
    *reinterpret_cast<ushort4*>(dst + F_DIM + f) = um;
}

// Kernel 2: combine chunk partials (4-way chunk-parallel + LDS reduce), fetch
// last row, write [last, mean, max]. Grid (B, 4): block (b,y) owns features
// [y*128, (y+1)*128).
__global__ __launch_bounds__(128) void scp_finalize(const float* __restrict__ x,
                                                    const int* __restrict__ lengths,
                                                    const ushort* __restrict__ ws,
                                                    float* __restrict__ out) {
    const int b = blockIdx.x;
    const int y = blockIdx.y;           // feature quarter
    const int tid = threadIdx.x;
    const int f4l = tid & 31;           // 32 float4 groups = 128 floats
    const int cpar = tid >> 5;          // 0..3 chunk-split lane
    const int f = y * 128 + f4l * 4;
    const int len = lengths[b];

    // issue last-row load early; latency hides under partial reads
    const float4 last = *reinterpret_cast<const float4*>(
        x + ((size_t)(len - 1) * B_DIM + b) * F_DIM + f);

    float4 sum = make_float4(0.f, 0.f, 0.f, 0.f);
    float4 mx = make_float4(-INFINITY, -INFINITY, -INFINITY, -INFINITY);

    #pragma unroll 4
    for (int c = cpar; c < NCHUNK; c += 4) {
        const ushort* src = ws + ((size_t)b * NCHUNK + c) * (2 * F_DIM);
        ushort4 s4 = *reinterpret_cast<const ushort4*>(src + f);
        ushort4 m4 = *reinterpret_cast<const ushort4*>(src + F_DIM + f);
        sum.x += bf16_val(s4.x); sum.y += bf16_val(s4.y);
        sum.z += bf16_val(s4.z); sum.w += bf16_val(s4.w);
        mx.x = fmaxf(mx.x, bf16_val(m4.x));
        mx.y = fmaxf(mx.y, bf16_val(m4.y));
        mx.z = fmaxf(mx.z, bf16_val(m4.z));
        mx.w = fmaxf(mx.w, bf16_val(m4.w));
    }

    __shared__ float4 ssum[4][32];
    __shared__ float4 smax[4][32];
    ssum[cpar][f4l] = sum;
    smax[cpar][f4l] = mx;
    __syncthreads();

    if (cpar == 0) {
        for (int k = 1; k < 4; ++k) {
            float4 s4 = ssum[k][f4l];
            float4 m4 = smax[k][f4l];
            sum.x += s4.x; sum.y += s4.y; sum.z += s4.z; sum.w += s4.w;
            mx.x = fmaxf(mx.x, m4.x);
            mx.y = fmaxf(mx.y, m4.y);
            mx.z = fmaxf(mx.z, m4.z);
            mx.w = fmaxf(mx.w, m4.w);
        }

        const float inv = 1.0f / (float)len;
        float4 mean = make_float4(sum.x * inv, sum.y * inv, sum.z * inv, sum.w * inv);

        float* ob = out + (size_t)b * (3 * F_DIM);
        *reinterpret_cast<float4*>(ob + f) = last;
        *reinterpret_cast<float4*>(ob + F_DIM + f) = mean;
        *reinterpret_cast<float4*>(ob + 2 * F_DIM + f) = mx;
    }
}

extern "C" void kernel_launch(void* const* d_in, const int* in_sizes, int n_in,
                              void* d_out, int out_size, void* d_ws, size_t ws_size,
                              hipStream_t stream) {
    const float* x = (const float*)d_in[0];
    const int* lengths = (const int*)d_in[1];
    float* out = (float*)d_out;
    ushort* ws = (ushort*)d_ws;

    scp_partial<<<dim3(NCHUNK, B_DIM), 128, 0, stream>>>(x, lengths, ws);
    scp_finalize<<<dim3(B_DIM, 4), 128, 0, stream>>>(x, lengths, ws, out);
}